// Round 1
// baseline (247.027 us; speedup 1.0000x reference)
//
#include <hip/hip_runtime.h>

#define BATCH 64
#define MAXD  448
#define PATCH 64
#define GRID7 7
#define NP    49   // 7*7 patches per image
#define TOPK  21

// ---------------------------------------------------------------------------
// Kernel 1: non-overlapping 64x64 average pool (we store the SUM — monotonic
// in the mean, so ranking is identical). One block per (batch, patch).
// ---------------------------------------------------------------------------
__global__ void pool_kernel(const float* __restrict__ hm, float* __restrict__ avg) {
    const int pid = blockIdx.x;          // b*49 + gr*7 + gc
    const int b  = pid / NP;
    const int p  = pid % NP;
    const int gr = p / GRID7, gc = p % GRID7;
    const float* base = hm + ((size_t)(b * MAXD + gr * PATCH) * MAXD) + gc * PATCH;

    // Patch = 64 rows x 64 cols = 1024 float4. 256 threads -> 4 float4 each.
    float s = 0.f;
    const int t = threadIdx.x;
    #pragma unroll
    for (int j = t; j < 1024; j += 256) {
        const int row = j >> 4;          // 16 float4 per row
        const int c4  = j & 15;
        const float4 v = *reinterpret_cast<const float4*>(base + (size_t)row * MAXD + c4 * 4);
        s += v.x + v.y + v.z + v.w;
    }
    // wave (64-lane) reduce
    #pragma unroll
    for (int off = 32; off > 0; off >>= 1) s += __shfl_down(s, off);
    __shared__ float ws[4];
    const int lane = t & 63, wid = t >> 6;
    if (lane == 0) ws[wid] = s;
    __syncthreads();
    if (t == 0) avg[pid] = ws[0] + ws[1] + ws[2] + ws[3];
}

// ---------------------------------------------------------------------------
// Kernel 2: per-batch stable top-21 by rank-counting (matches jax.lax.top_k:
// descending, ties broken toward lower index). One 64-thread block per batch.
// ---------------------------------------------------------------------------
__global__ void topk_kernel(const float* __restrict__ avg, int* __restrict__ idx) {
    const int b = blockIdx.x;
    const int t = threadIdx.x;
    __shared__ float v[NP];
    if (t < NP) v[t] = avg[b * NP + t];
    __syncthreads();
    if (t < NP) {
        const float mine = v[t];
        int rank = 0;
        #pragma unroll
        for (int j = 0; j < NP; ++j) {
            const float o = v[j];
            rank += (o > mine || (o == mine && j < t)) ? 1 : 0;
        }
        if (rank < TOPK) idx[b * TOPK + rank] = t;
    }
}

// ---------------------------------------------------------------------------
// Kernel 3: gather selected patches. One block per output patch (1344).
// Patch row segment = 64*3 = 192 floats = 48 float4, 16B-aligned everywhere.
// ---------------------------------------------------------------------------
__global__ void gather_kernel(const float* __restrict__ img,
                              const int* __restrict__ idx,
                              float* __restrict__ out) {
    const int o = blockIdx.x;            // b*21 + k
    const int b = o / TOPK;
    const int p = idx[o];
    const int gr = p / GRID7, gc = p % GRID7;

    const float4* __restrict__ src = reinterpret_cast<const float4*>(
        img + ((size_t)(b * MAXD + gr * PATCH) * MAXD + gc * PATCH) * 3);
    float4* __restrict__ dst = reinterpret_cast<float4*>(
        out + (size_t)o * (PATCH * PATCH * 3));

    // 3072 float4 per patch; src row stride = 448*3/4 = 336 float4.
    for (int j = threadIdx.x; j < 3072; j += 256) {
        const int row = j / 48;
        const int c   = j - row * 48;
        dst[j] = src[(size_t)row * 336 + c];
    }
}

// ---------------------------------------------------------------------------
extern "C" void kernel_launch(void* const* d_in, const int* in_sizes, int n_in,
                              void* d_out, int out_size, void* d_ws, size_t ws_size,
                              hipStream_t stream) {
    const float* hm  = (const float*)d_in[0];   // heatmap [64,448,448,1] f32
    const float* img = (const float*)d_in[1];   // image   [64,448,448,3] f32
    float* out = (float*)d_out;                 // [1344,64,64,3] f32

    float* avg = (float*)d_ws;                              // 64*49 floats
    int*   idx = (int*)((char*)d_ws + BATCH * NP * sizeof(float)); // 64*21 ints

    pool_kernel  <<<BATCH * NP, 256, 0, stream>>>(hm, avg);
    topk_kernel  <<<BATCH,       64, 0, stream>>>(avg, idx);
    gather_kernel<<<BATCH * TOPK, 256, 0, stream>>>(img, idx, out);
}